// Round 16
// baseline (392.692 us; speedup 1.0000x reference)
//
#include <hip/hip_runtime.h>
#include <hip/hip_bf16.h>

#define NN 50000      // nodes
#define NE 200000     // edges
#define NGR 500       // graphs
#define HD 128        // hidden
#define CDIM 256      // H*DH
#define NLAY 4
#define NVOC 30
#define NCAT 896      // 256*3 + 128 : Q | KV-interleaved | R
#define SCH 256                       // scan chunk
#define SNB ((NN + SCH - 1) / SCH)    // 196 scan blocks
#define GP 7                          // gemm column panels
#define CBP (56 / GP)                 // cb iters per panel = 8 (128 cols)
#define WPAN (CBP * 4 * 512)          // 16384 ushorts = 32 KB W panel

// fused setup kernel block ranges
#define SU_TBLN 30                    // [0,30): node table rows
#define SU_TBLE (NLAY * NVOC)         // [30,150): etab rows
#define SU_PKW  (NLAY * 224 / 4)      // [150,374): packw, 4 sub-blocks each
#define SU_HIST ((NE + 255) / 256)    // [374,1156): dst histogram
#define SU_NBLK (SU_TBLN + SU_TBLE + SU_PKW + SU_HIST)

static constexpr float BN_INV = 0.9999950000374997f;  // 1/sqrt(1+1e-5)

typedef __attribute__((ext_vector_type(8))) short bf16x8;
typedef __attribute__((ext_vector_type(4))) float f32x4;
typedef __attribute__((ext_vector_type(2))) float f32x2;

__device__ __forceinline__ float bf2f(unsigned short u) {
    return __uint_as_float(((unsigned)u) << 16);
}
__device__ __forceinline__ unsigned short f2bf(float f) {
    union { __hip_bfloat16 h; unsigned short u; } cv;
    cv.h = __float2bfloat16(f);
    return cv.u;
}
// unpack u32 holding 2 bf16 -> f32x2 {lo, hi}
__device__ __forceinline__ f32x2 up2(unsigned u) {
    f32x2 r;
    r.x = __uint_as_float(u << 16);
    r.y = __uint_as_float(u & 0xffff0000u);
    return r;
}
// leaky_relu(z, 0.2) elementwise on a pair
__device__ __forceinline__ f32x2 lk2(f32x2 z) {
    f32x2 zero = {0.f, 0.f};
    return __builtin_elementwise_max(z, zero) + 0.2f * __builtin_elementwise_min(z, zero);
}

// ---------------- fused setup: node table | etab | packw | hist ----------------
__global__ __launch_bounds__(256) void k_setup(
    const float* __restrict__ ne,
    const float* __restrict__ w1, const float* __restrict__ b1,
    const float* __restrict__ g1, const float* __restrict__ bt1,
    const float* __restrict__ w2, const float* __restrict__ b2,
    const float* __restrict__ g0, const float* __restrict__ bt0,
    const float* __restrict__ We,
    const float* __restrict__ Wq, const float* __restrict__ Wk,
    const float* __restrict__ Wv, const float* __restrict__ Wr,
    const int* __restrict__ ei,
    float* __restrict__ x0tab, unsigned short* __restrict__ etab,
    unsigned short* __restrict__ Wpk, int* __restrict__ cnt)
{
    __shared__ float smem[256];
    int b = blockIdx.x, t = threadIdx.x;
    if (b < SU_TBLN) {
        int r = b, d = t;
        if (d < HD) smem[d] = ne[r * HD + d];
        __syncthreads();
        float v1 = 0.f;
        if (d < HD) {
            float acc = b1[d];
            for (int k = 0; k < HD; ++k) acc += smem[k] * w1[k * HD + d];
            v1 = fmaxf(acc * BN_INV * g1[d] + bt1[d], 0.f);
        }
        __syncthreads();
        if (d < HD) smem[HD + d] = v1;
        __syncthreads();
        if (d < HD) {
            float acc2 = b2[d];
            for (int k = 0; k < HD; ++k) acc2 += smem[HD + k] * w2[k * HD + d];
            x0tab[r * HD + d] = fmaxf(acc2 * BN_INV * g0[d] + bt0[d], 0.f);
        }
    } else if (b < SU_TBLN + SU_TBLE) {
        int la = b - SU_TBLN;
        int l = la / NVOC, a = la % NVOC;
        int c = t;
        if (c < HD) smem[c] = ne[a * HD + c];
        __syncthreads();
        const float* W = We + (size_t)l * HD * CDIM;
        float acc = 0.f;
        for (int k = 0; k < HD; ++k) acc += smem[k] * W[k * CDIM + c];
        etab[(size_t)la * CDIM + c] = f2bf(acc);
    } else if (b < SU_TBLN + SU_TBLE + SU_PKW) {
        int bb = (b - SU_TBLN - SU_TBLE) * 4 + (t >> 6);   // [0, NLAY*224)
        int lane = t & 63;
        int l = bb / 224, rem = bb % 224;
        int kb = rem / 56, jb = rem % 56;
        int j = jb * 16 + (lane & 15);
        int kbase = kb * 32 + ((lane >> 4) << 3);
        unsigned short* dst = Wpk + ((size_t)bb * 64 + lane) * 8;
#pragma unroll
        for (int tt = 0; tt < 8; ++tt) {
            int k = kbase + tt;
            float v;
            if (j < 256) {
                v = Wq[((size_t)l * HD + k) * CDIM + j];
            } else if (j < 768) {
                int t2 = j - 256, g = t2 >> 3, r = t2 & 7;
                int c = g * 4 + (r & 3);
                v = (r < 4) ? Wk[((size_t)l * HD + k) * CDIM + c]
                            : Wv[((size_t)l * HD + k) * CDIM + c];
            } else {
                v = Wr[((size_t)l * HD + k) * HD + (j - 768)];
            }
            dst[tt] = f2bf(v);
        }
    } else {
        int e = (b - SU_TBLN - SU_TBLE - SU_PKW) * 256 + t;
        if (e < NE) atomicAdd(&cnt[ei[NE + e]], 1);
    }
}

// ---------------- CSR scan ----------------
__global__ __launch_bounds__(256) void k_blocksum(const int* __restrict__ cnt, int* __restrict__ part)
{
    int t = threadIdx.x;
    int i = blockIdx.x * SCH + t;
    int v = (i < NN) ? cnt[i] : 0;
    __shared__ int sm[256];
    sm[t] = v;
    __syncthreads();
    for (int off = 128; off; off >>= 1) {
        if (t < off) sm[t] += sm[t + off];
        __syncthreads();
    }
    if (t == 0) part[blockIdx.x] = sm[0];
}

__global__ __launch_bounds__(256) void k_scanpart(int* __restrict__ part)
{
    int t = threadIdx.x;
    int v = (t < SNB) ? part[t] : 0;
    __shared__ int sm[256];
    sm[t] = v;
    __syncthreads();
    for (int off = 1; off < 256; off <<= 1) {
        int u = (t >= off) ? sm[t - off] : 0;
        __syncthreads();
        sm[t] += u;
        __syncthreads();
    }
    if (t < SNB) part[t] = sm[t] - v;   // exclusive
}

__global__ __launch_bounds__(256) void k_csrwrite(
    const int* __restrict__ cnt, const int* __restrict__ part,
    int* __restrict__ rowp, int* __restrict__ wof)
{
    int t = threadIdx.x;
    int i = blockIdx.x * SCH + t;
    int v = (i < NN) ? cnt[i] : 0;
    __shared__ int sm[256];
    sm[t] = v;
    __syncthreads();
    for (int off = 1; off < 256; off <<= 1) {
        int u = (t >= off) ? sm[t - off] : 0;
        __syncthreads();
        sm[t] += u;
        __syncthreads();
    }
    int excl = sm[t] - v + part[blockIdx.x];
    if (i < NN) { rowp[i] = excl; wof[i] = excl; }
    if (i == NN - 1) rowp[NN] = excl + v;   // = NE
}

// scatter (src, edge_attr) pairs into CSR order as int2
__global__ void k_scatter(const int* __restrict__ ei, const int* __restrict__ ea,
                          int* __restrict__ wof, int2* __restrict__ cse)
{
    int e = blockIdx.x * blockDim.x + threadIdx.x;
    if (e < NE) {
        int d = ei[NE + e];
        int pos = atomicAdd(&wof[d], 1);
        int2 v; v.x = ei[e]; v.y = ea[e];
        cse[pos] = v;
    }
}

// ---------------- x0b[n] = bf16(x0table[x[n]])  (+ fused gptr) ----------------
__global__ void k_x0(const int* __restrict__ x, const float* __restrict__ tab,
                     unsigned short* __restrict__ x0b,
                     const int* __restrict__ batch, int* __restrict__ gptr)
{
    int idx = blockIdx.x * blockDim.x + threadIdx.x;  // NN*32 float4 slots
    if (idx <= NGR) {
        if (idx == NGR) gptr[idx] = NN;
        else {
            int lo = 0, hi = NN;
            while (lo < hi) { int mid = (lo + hi) >> 1; if (batch[mid] < idx) lo = mid + 1; else hi = mid; }
            gptr[idx] = lo;
        }
    }
    if (idx >= NN * 32) return;
    int n = idx >> 5, c = idx & 31;
    float4 v = *(const float4*)&tab[x[n] * HD + c * 4];
    ushort4 u; u.x = f2bf(v.x); u.y = f2bf(v.y); u.z = f2bf(v.z); u.w = f2bf(v.w);
    *(ushort4*)&x0b[(size_t)n * HD + c * 4] = u;
}

// ---------------- bf16 MFMA GEMM: LDS-staged W panel + LDS-staged stores ------
// R15 diagnosis: all 4 waves of a block loaded the SAME 32 KB W panel from
// L1/L2 (up to 4x redundant, ~half the cycle budget in W movement + ~200cyc
// L2 latency per load the MFMA chains can't hide). Fix: cooperative stage
// panel into LDS once, ds_read_b128 fragments (~12 cyc), 8 independent
// 4-MFMA chains (acc[8], all compile-time indexed). LDS reused as the 64x136
// output tile for the coalesced-store phase (R9 win kept).
__global__ __launch_bounds__(256) void k_gemm(
    const unsigned short* __restrict__ Ab, const unsigned short* __restrict__ Wpk,
    unsigned short* __restrict__ C)
{
    __shared__ unsigned short smem[WPAN];   // 32 KB: W panel, then 64x136 tile
    int tid = threadIdx.x;
    int lane = tid & 63, wid = tid >> 6;
    int nb = blockIdx.x * 64;
    int rowl = wid * 16 + (lane & 15);
    int node = nb + rowl;
    size_t arow = (size_t)((node < NN) ? node : (NN - 1));
    int ko = (lane >> 4) << 3;
    const unsigned short* ap = Ab + arow * HD + ko;
    bf16x8 a0 = *(const bf16x8*)(ap);
    bf16x8 a1 = *(const bf16x8*)(ap + 32);
    bf16x8 a2 = *(const bf16x8*)(ap + 64);
    bf16x8 a3 = *(const bf16x8*)(ap + 96);

    // stage the 32 KB W panel: 2048 x 16B chunks, coalesced
    int cb0 = blockIdx.y * CBP;
    const unsigned short* wsrc = Wpk + (size_t)cb0 * 512;
#pragma unroll
    for (int it = 0; it < 8; ++it) {
        int idx = it * 256 + tid;          // 0..2047
        int g = idx >> 6;                  // 1KB unit id: i = g>>2 (cb), kb = g&3
        int e = (idx & 63) * 8;            // ushort offset within unit
        *(uint4*)&smem[g * 512 + e] =
            *(const uint4*)&wsrc[(size_t)(g >> 2) * 512 + (size_t)(g & 3) * 28672 + e];
    }
    __syncthreads();

    f32x4 acc[CBP];
#pragma unroll
    for (int i = 0; i < CBP; ++i) acc[i] = (f32x4){0.f, 0.f, 0.f, 0.f};
    int lo = lane * 8;
#pragma unroll
    for (int i = 0; i < CBP; ++i) {
        bf16x8 w0 = *(const bf16x8*)&smem[(i * 4 + 0) * 512 + lo];
        bf16x8 w1 = *(const bf16x8*)&smem[(i * 4 + 1) * 512 + lo];
        bf16x8 w2 = *(const bf16x8*)&smem[(i * 4 + 2) * 512 + lo];
        bf16x8 w3 = *(const bf16x8*)&smem[(i * 4 + 3) * 512 + lo];
        acc[i] = __builtin_amdgcn_mfma_f32_16x16x32_bf16(w0, a0, acc[i], 0, 0, 0);
        acc[i] = __builtin_amdgcn_mfma_f32_16x16x32_bf16(w1, a1, acc[i], 0, 0, 0);
        acc[i] = __builtin_amdgcn_mfma_f32_16x16x32_bf16(w2, a2, acc[i], 0, 0, 0);
        acc[i] = __builtin_amdgcn_mfma_f32_16x16x32_bf16(w3, a3, acc[i], 0, 0, 0);
    }
    __syncthreads();   // all waves done reading W before tile overwrite

    int jreg = (lane >> 4) << 2;
#pragma unroll
    for (int i = 0; i < CBP; ++i) {
        uint2 o;
        o.x = (unsigned)f2bf(acc[i][0]) | ((unsigned)f2bf(acc[i][1]) << 16);
        o.y = (unsigned)f2bf(acc[i][2]) | ((unsigned)f2bf(acc[i][3]) << 16);
        *(uint2*)&smem[rowl * 136 + i * 16 + jreg] = o;
    }
    __syncthreads();
    int r0 = tid >> 4;                    // 0..15
    int cseg = (tid & 15) * 8;            // bf16 col offset, 16B per lane
#pragma unroll
    for (int pass = 0; pass < 4; ++pass) {
        int row = pass * 16 + r0;
        int gnode = nb + row;
        if (gnode < NN) {
            uint4 v = *(const uint4*)&smem[row * 136 + cseg];
            *(uint4*)&C[(size_t)gnode * NCAT + cb0 * 16 + cseg] = v;
        }
    }
}

// ---------------- per-node attention: ONE WAVE PER WORKGROUP ------------------
// (R15 win: independent wave retirement removes Poisson-degree stragglers.)
// Body: 2-edge ILP, packed f32x2 math, 32 VGPR.
__global__ __launch_bounds__(64) void k_edge(
    const unsigned short* __restrict__ QKVR,  // [NN][896] bf16, Q|KVint|R
    const unsigned short* __restrict__ etab,  // layer slice [30][256] bf16
    const float* __restrict__ attL, const float* __restrict__ biasL,
    const unsigned short* __restrict__ x0b,
    const int* __restrict__ rowptr, const int2* __restrict__ cse,
    unsigned short* __restrict__ hb)          // [NN][128] bf16
{
    int n = blockIdx.x;
    int lane = threadIdx.x & 63;
    int head = lane >> 5, sub = lane & 31;
    int col = head * HD + sub * 4;             // dim index (Q/etab/att layout)
    int kvo = 256 + head * 256 + sub * 8;      // KV-interleaved offset

    uint2 quu = *(const uint2*)&QKVR[(size_t)n * NCAT + col];
    f32x2 q0 = up2(quu.x), q1 = up2(quu.y);
    float4 a4 = *(const float4*)&attL[col];
    f32x2 av0 = {a4.x, a4.y}, av1 = {a4.z, a4.w};

    float l0 = 0.f, l1 = 0.f;
    f32x2 accA0 = {0.f, 0.f}, accA1 = {0.f, 0.f};
    f32x2 accB0 = {0.f, 0.f}, accB1 = {0.f, 0.f};

    int beg = rowptr[n], end = rowptr[n + 1];
    int idx = beg;
    for (; idx + 1 < end; idx += 2) {
        int2 seA = cse[idx];
        int2 seB = cse[idx + 1];
        uint4 kvA = *(const uint4*)&QKVR[(size_t)seA.x * NCAT + kvo];
        uint4 kvB = *(const uint4*)&QKVR[(size_t)seB.x * NCAT + kvo];
        uint2 euA = *(const uint2*)&etab[seA.y * CDIM + col];
        uint2 euB = *(const uint2*)&etab[seB.y * CDIM + col];

        f32x2 eA0 = up2(euA.x), eA1 = up2(euA.y);
        f32x2 eB0 = up2(euB.x), eB1 = up2(euB.y);

        f32x2 zA0 = lk2(q0 + up2(kvA.x) + eA0);
        f32x2 zA1 = lk2(q1 + up2(kvA.y) + eA1);
        f32x2 zB0 = lk2(q0 + up2(kvB.x) + eB0);
        f32x2 zB1 = lk2(q1 + up2(kvB.y) + eB1);

        f32x2 ppA = zA0 * av0 + zA1 * av1;
        f32x2 ppB = zB0 * av0 + zB1 * av1;
        float pA = ppA.x + ppA.y;
        float pB = ppB.x + ppB.y;
        pA += __shfl_xor(pA, 16); pB += __shfl_xor(pB, 16);
        pA += __shfl_xor(pA, 8);  pB += __shfl_xor(pB, 8);
        pA += __shfl_xor(pA, 4);  pB += __shfl_xor(pB, 4);
        pA += __shfl_xor(pA, 2);  pB += __shfl_xor(pB, 2);
        pA += __shfl_xor(pA, 1);  pB += __shfl_xor(pB, 1);
        float peA = __expf(fminf(fmaxf(pA, -30.f), 30.f));
        float peB = __expf(fminf(fmaxf(pB, -30.f), 30.f));

        accA0 += peA * (up2(kvA.z) + eA0);
        accA1 += peA * (up2(kvA.w) + eA1);
        accB0 += peB * (up2(kvB.z) + eB0);
        accB1 += peB * (up2(kvB.w) + eB1);
        l0 += peA;
        l1 += peB;
    }
    if (idx < end) {
        int2 se = cse[idx];
        uint4 kv = *(const uint4*)&QKVR[(size_t)se.x * NCAT + kvo];
        uint2 eu = *(const uint2*)&etab[se.y * CDIM + col];
        f32x2 e0 = up2(eu.x), e1 = up2(eu.y);
        f32x2 z0 = lk2(q0 + up2(kv.x) + e0);
        f32x2 z1 = lk2(q1 + up2(kv.y) + e1);
        f32x2 pp = z0 * av0 + z1 * av1;
        float p = pp.x + pp.y;
        p += __shfl_xor(p, 16); p += __shfl_xor(p, 8);
        p += __shfl_xor(p, 4);  p += __shfl_xor(p, 2); p += __shfl_xor(p, 1);
        float pe = __expf(fminf(fmaxf(p, -30.f), 30.f));
        accA0 += pe * (up2(kv.z) + e0);
        accA1 += pe * (up2(kv.w) + e1);
        l0 += pe;
    }
    float l = l0 + l1;
    float invl = (l > 0.f) ? 1.0f / l : 0.f;
    f32x2 r0 = (accA0 + accB0) * invl;
    f32x2 r1 = (accA1 + accB1) * invl;
    // mean over heads: pair lane <-> lane^32
    r0.x = 0.5f * (r0.x + __shfl_xor(r0.x, 32));
    r0.y = 0.5f * (r0.y + __shfl_xor(r0.y, 32));
    r1.x = 0.5f * (r1.x + __shfl_xor(r1.x, 32));
    r1.y = 0.5f * (r1.y + __shfl_xor(r1.y, 32));
    if (head == 0) {
        uint2 ruu = *(const uint2*)&QKVR[(size_t)n * NCAT + 768 + sub * 4];
        f32x2 ru0 = up2(ruu.x), ru1 = up2(ruu.y);
        float4 b4 = *(const float4*)&biasL[sub * 4];
        f32x2 bb0 = {b4.x, b4.y}, bb1 = {b4.z, b4.w};
        uint2 xuu = *(const uint2*)&x0b[(size_t)n * HD + sub * 4];
        f32x2 xx0 = up2(xuu.x), xx1 = up2(xuu.y);
        f32x2 zero = {0.f, 0.f};
        f32x2 h0 = 0.9f * __builtin_elementwise_max(r0 + ru0 + bb0, zero) + 0.1f * xx0;
        f32x2 h1 = 0.9f * __builtin_elementwise_max(r1 + ru1 + bb1, zero) + 0.1f * xx1;
        ushort4 o;
        o.x = f2bf(h0.x); o.y = f2bf(h0.y); o.z = f2bf(h1.x); o.w = f2bf(h1.y);
        *(ushort4*)&hb[(size_t)n * HD + sub * 4] = o;
    }
}

// ---------------- pooling: grid (graph, slice), vectorized uint2 loads --------
__global__ __launch_bounds__(256) void k_poolall(
    const unsigned short* __restrict__ x0b,
    const unsigned short* __restrict__ h0, const unsigned short* __restrict__ h1,
    const unsigned short* __restrict__ h2, const unsigned short* __restrict__ h3,
    const int* __restrict__ gptr, float* __restrict__ gsum)
{
    int g = blockIdx.x, sl = blockIdx.y;
    const unsigned short* src = (sl == 0) ? x0b : (sl == 1) ? h0 : (sl == 2) ? h1
                              : (sl == 3) ? h2 : h3;
    int q = threadIdx.x & 31;     // dim quad: dims q*4 .. q*4+3
    int r = threadIdx.x >> 5;     // row group 0..7
    int beg = gptr[g], end = gptr[g + 1];
    float sx = 0.f, sy = 0.f, sz = 0.f, sw = 0.f;
    for (int n = beg + r; n < end; n += 8) {
        uint2 u = *(const uint2*)&src[(size_t)n * HD + q * 4];
        sx += __uint_as_float(u.x << 16);
        sy += __uint_as_float(u.x & 0xffff0000u);
        sz += __uint_as_float(u.y << 16);
        sw += __uint_as_float(u.y & 0xffff0000u);
    }
    __shared__ float4 sm[8][32];
    float4 s4 = {sx, sy, sz, sw};
    sm[r][q] = s4;
    __syncthreads();
    if (r == 0) {
        float4 t = sm[0][q];
#pragma unroll
        for (int j = 1; j < 8; ++j) {
            float4 u = sm[j][q];
            t.x += u.x; t.y += u.y; t.z += u.z; t.w += u.w;
        }
        *(float4*)&gsum[(size_t)g * 640 + sl * HD + q * 4] = t;
    }
}

// ---------------- final MLP: g[640] -> 128 -> 1 ----------------
__global__ __launch_bounds__(128) void k_out(
    const float* __restrict__ gsum, const int* __restrict__ gptr,
    const float* __restrict__ w1, const float* __restrict__ b1,
    const float* __restrict__ g1, const float* __restrict__ bt1,
    const float* __restrict__ w2, const float* __restrict__ b2,
    float* __restrict__ out)
{
    int g = blockIdx.x, d = threadIdx.x;
    __shared__ float row[640];
    __shared__ float red[2];
    int c = gptr[g + 1] - gptr[g];
    float invc = 1.0f / (float)max(c, 1);
    for (int j = d; j < 640; j += 128) row[j] = gsum[(size_t)g * 640 + j] * invc;
    __syncthreads();
    float acc = b1[d];
    for (int j = 0; j < 640; ++j) acc += row[j] * w1[j * HD + d];
    float val = fmaxf(acc * BN_INV * g1[d] + bt1[d], 0.f);
    float part = val * w2[d];
    part += __shfl_xor(part, 32); part += __shfl_xor(part, 16);
    part += __shfl_xor(part, 8);  part += __shfl_xor(part, 4);
    part += __shfl_xor(part, 2);  part += __shfl_xor(part, 1);
    if ((threadIdx.x & 63) == 0) red[threadIdx.x >> 6] = part;
    __syncthreads();
    if (threadIdx.x == 0) out[g] = red[0] + red[1] + b2[0];
}

// ---------------- launch ----------------
extern "C" void kernel_launch(void* const* d_in, const int* in_sizes, int n_in,
                              void* d_out, int out_size, void* d_ws, size_t ws_size,
                              hipStream_t stream)
{
    const int*   x        = (const int*)d_in[0];
    const int*   ei       = (const int*)d_in[1];
    const int*   ea       = (const int*)d_in[2];
    const int*   batch    = (const int*)d_in[3];
    const float* node_emb = (const float*)d_in[4];
    const float* emb_w1   = (const float*)d_in[5];
    const float* emb_b1   = (const float*)d_in[6];
    const float* emb_g1   = (const float*)d_in[7];
    const float* emb_bt1  = (const float*)d_in[8];
    const float* emb_w2   = (const float*)d_in[9];
    const float* emb_b2   = (const float*)d_in[10];
    const float* bn0_g    = (const float*)d_in[11];
    const float* bn0_b    = (const float*)d_in[12];
    const float* Wq       = (const float*)d_in[13];
    const float* Wk       = (const float*)d_in[14];
    const float* Wv       = (const float*)d_in[15];
    const float* We       = (const float*)d_in[16];
    const float* att      = (const float*)d_in[17];
    const float* Wroot    = (const float*)d_in[18];
    const float* bias     = (const float*)d_in[19];
    const float* out_w1   = (const float*)d_in[20];
    const float* out_b1   = (const float*)d_in[21];
    const float* out_g1   = (const float*)d_in[22];
    const float* out_bt1  = (const float*)d_in[23];
    const float* out_w2   = (const float*)d_in[24];
    const float* out_b2   = (const float*)d_in[25];

    char* wp = (char*)d_ws;
    auto alloc = [&](size_t bytes) -> void* {
        void* p = (void*)wp;
        wp += (bytes + 255) & ~(size_t)255;
        return p;
    };
    unsigned short* x0b   = (unsigned short*)alloc((size_t)NN * HD * 2);
    unsigned short* hb0   = (unsigned short*)alloc((size_t)NN * HD * 2);
    unsigned short* hb1   = (unsigned short*)alloc((size_t)NN * HD * 2);
    unsigned short* hb2   = (unsigned short*)alloc((size_t)NN * HD * 2);
    unsigned short* hb3   = (unsigned short*)alloc((size_t)NN * HD * 2);
    unsigned short* QKVR  = (unsigned short*)alloc((size_t)NN * NCAT * 2);
    float*          x0tab = (float*)alloc((size_t)NVOC * HD * 4);
    unsigned short* etab  = (unsigned short*)alloc((size_t)NLAY * NVOC * CDIM * 2);
    unsigned short* Wpk   = (unsigned short*)alloc((size_t)NLAY * 224 * 64 * 8 * 2);
    int*   cnt   = (int*)alloc((size_t)NN * 4);
    int*   rowp  = (int*)alloc((size_t)(NN + 1) * 4);
    int*   wof   = (int*)alloc((size_t)(NN + 1) * 4);
    int*   part  = (int*)alloc((size_t)SNB * 4);
    int2*  cse   = (int2*)alloc((size_t)NE * 8);
    int*   gptr  = (int*)alloc((size_t)(NGR + 1) * 4);
    float* gsum  = (float*)alloc((size_t)NGR * 640 * 4);

    hipMemsetAsync(cnt, 0, (size_t)NN * 4, stream);

    k_setup<<<SU_NBLK, 256, 0, stream>>>(
        node_emb, emb_w1, emb_b1, emb_g1, emb_bt1, emb_w2, emb_b2, bn0_g, bn0_b,
        We, Wq, Wk, Wv, Wroot, ei, x0tab, etab, Wpk, cnt);
    k_blocksum<<<SNB, 256, 0, stream>>>(cnt, part);
    k_scanpart<<<1, 256, 0, stream>>>(part);
    k_csrwrite<<<SNB, 256, 0, stream>>>(cnt, part, rowp, wof);
    k_scatter<<<(NE + 255) / 256, 256, 0, stream>>>(ei, ea, wof, cse);
    k_x0<<<(NN * 32 + 255) / 256, 256, 0, stream>>>(x, x0tab, x0b, batch, gptr);

    const unsigned short* hin = x0b;
    unsigned short* houts[NLAY] = {hb0, hb1, hb2, hb3};
    for (int l = 0; l < NLAY; ++l) {
        k_gemm<<<dim3((NN + 63) / 64, GP), 256, 0, stream>>>(
            hin, Wpk + (size_t)l * 224 * 512, QKVR);
        k_edge<<<NN, 64, 0, stream>>>(
            QKVR, etab + (size_t)l * NVOC * CDIM, att + (size_t)l * CDIM, bias + (size_t)l * HD,
            x0b, rowp, cse, houts[l]);
        hin = houts[l];
    }
    k_poolall<<<dim3(NGR, 5), 256, 0, stream>>>(x0b, hb0, hb1, hb2, hb3, gptr, gsum);
    k_out<<<NGR, 128, 0, stream>>>(gsum, gptr, out_w1, out_b1, out_g1, out_bt1,
                                   out_w2, out_b2, (float*)d_out);
}

// Round 17
// 381.944 us; speedup vs baseline: 1.0281x; 1.0281x over previous
//
#include <hip/hip_runtime.h>
#include <hip/hip_bf16.h>

#define NN 50000      // nodes
#define NE 200000     // edges
#define NGR 500       // graphs
#define HD 128        // hidden
#define CDIM 256      // H*DH
#define NLAY 4
#define NVOC 30
#define NCAT 896      // 256*3 + 128 : Q | KV-interleaved | R
#define SCH 256                       // scan chunk
#define SNB ((NN + SCH - 1) / SCH)    // 196 scan blocks
#define GP 7                          // gemm column panels
#define CBP (56 / GP)                 // cb iters per panel = 8 (128 cols)
#define NBK ((NN + 63) / 64)          // 782 node blocks
#define GGRID (((NBK + 7) / 8) * GP * 8)   // 98*7*8 = 5488 remapped blocks

// fused setup kernel block ranges
#define SU_TBLN 30                    // [0,30): node table rows
#define SU_TBLE (NLAY * NVOC)         // [30,150): etab rows
#define SU_PKW  (NLAY * 224 / 4)      // [150,374): packw, 4 sub-blocks each
#define SU_HIST ((NE + 255) / 256)    // [374,1156): dst histogram
#define SU_NBLK (SU_TBLN + SU_TBLE + SU_PKW + SU_HIST)

static constexpr float BN_INV = 0.9999950000374997f;  // 1/sqrt(1+1e-5)

typedef __attribute__((ext_vector_type(8))) short bf16x8;
typedef __attribute__((ext_vector_type(4))) float f32x4;
typedef __attribute__((ext_vector_type(2))) float f32x2;

__device__ __forceinline__ float bf2f(unsigned short u) {
    return __uint_as_float(((unsigned)u) << 16);
}
__device__ __forceinline__ unsigned short f2bf(float f) {
    union { __hip_bfloat16 h; unsigned short u; } cv;
    cv.h = __float2bfloat16(f);
    return cv.u;
}
// unpack u32 holding 2 bf16 -> f32x2 {lo, hi}
__device__ __forceinline__ f32x2 up2(unsigned u) {
    f32x2 r;
    r.x = __uint_as_float(u << 16);
    r.y = __uint_as_float(u & 0xffff0000u);
    return r;
}
// leaky_relu(z, 0.2) elementwise on a pair
__device__ __forceinline__ f32x2 lk2(f32x2 z) {
    f32x2 zero = {0.f, 0.f};
    return __builtin_elementwise_max(z, zero) + 0.2f * __builtin_elementwise_min(z, zero);
}

// ---------------- fused setup: node table | etab | packw | hist ----------------
__global__ __launch_bounds__(256) void k_setup(
    const float* __restrict__ ne,
    const float* __restrict__ w1, const float* __restrict__ b1,
    const float* __restrict__ g1, const float* __restrict__ bt1,
    const float* __restrict__ w2, const float* __restrict__ b2,
    const float* __restrict__ g0, const float* __restrict__ bt0,
    const float* __restrict__ We,
    const float* __restrict__ Wq, const float* __restrict__ Wk,
    const float* __restrict__ Wv, const float* __restrict__ Wr,
    const int* __restrict__ ei,
    float* __restrict__ x0tab, unsigned short* __restrict__ etab,
    unsigned short* __restrict__ Wpk, int* __restrict__ cnt)
{
    __shared__ float smem[256];
    int b = blockIdx.x, t = threadIdx.x;
    if (b < SU_TBLN) {
        int r = b, d = t;
        if (d < HD) smem[d] = ne[r * HD + d];
        __syncthreads();
        float v1 = 0.f;
        if (d < HD) {
            float acc = b1[d];
            for (int k = 0; k < HD; ++k) acc += smem[k] * w1[k * HD + d];
            v1 = fmaxf(acc * BN_INV * g1[d] + bt1[d], 0.f);
        }
        __syncthreads();
        if (d < HD) smem[HD + d] = v1;
        __syncthreads();
        if (d < HD) {
            float acc2 = b2[d];
            for (int k = 0; k < HD; ++k) acc2 += smem[HD + k] * w2[k * HD + d];
            x0tab[r * HD + d] = fmaxf(acc2 * BN_INV * g0[d] + bt0[d], 0.f);
        }
    } else if (b < SU_TBLN + SU_TBLE) {
        int la = b - SU_TBLN;
        int l = la / NVOC, a = la % NVOC;
        int c = t;
        if (c < HD) smem[c] = ne[a * HD + c];
        __syncthreads();
        const float* W = We + (size_t)l * HD * CDIM;
        float acc = 0.f;
        for (int k = 0; k < HD; ++k) acc += smem[k] * W[k * CDIM + c];
        etab[(size_t)la * CDIM + c] = f2bf(acc);
    } else if (b < SU_TBLN + SU_TBLE + SU_PKW) {
        int bb = (b - SU_TBLN - SU_TBLE) * 4 + (t >> 6);   // [0, NLAY*224)
        int lane = t & 63;
        int l = bb / 224, rem = bb % 224;
        int kb = rem / 56, jb = rem % 56;
        int j = jb * 16 + (lane & 15);
        int kbase = kb * 32 + ((lane >> 4) << 3);
        unsigned short* dst = Wpk + ((size_t)bb * 64 + lane) * 8;
#pragma unroll
        for (int tt = 0; tt < 8; ++tt) {
            int k = kbase + tt;
            float v;
            if (j < 256) {
                v = Wq[((size_t)l * HD + k) * CDIM + j];
            } else if (j < 768) {
                int t2 = j - 256, g = t2 >> 3, r = t2 & 7;
                int c = g * 4 + (r & 3);
                v = (r < 4) ? Wk[((size_t)l * HD + k) * CDIM + c]
                            : Wv[((size_t)l * HD + k) * CDIM + c];
            } else {
                v = Wr[((size_t)l * HD + k) * HD + (j - 768)];
            }
            dst[tt] = f2bf(v);
        }
    } else {
        int e = (b - SU_TBLN - SU_TBLE - SU_PKW) * 256 + t;
        if (e < NE) atomicAdd(&cnt[ei[NE + e]], 1);
    }
}

// ---------------- CSR scan ----------------
__global__ __launch_bounds__(256) void k_blocksum(const int* __restrict__ cnt, int* __restrict__ part)
{
    int t = threadIdx.x;
    int i = blockIdx.x * SCH + t;
    int v = (i < NN) ? cnt[i] : 0;
    __shared__ int sm[256];
    sm[t] = v;
    __syncthreads();
    for (int off = 128; off; off >>= 1) {
        if (t < off) sm[t] += sm[t + off];
        __syncthreads();
    }
    if (t == 0) part[blockIdx.x] = sm[0];
}

__global__ __launch_bounds__(256) void k_scanpart(int* __restrict__ part)
{
    int t = threadIdx.x;
    int v = (t < SNB) ? part[t] : 0;
    __shared__ int sm[256];
    sm[t] = v;
    __syncthreads();
    for (int off = 1; off < 256; off <<= 1) {
        int u = (t >= off) ? sm[t - off] : 0;
        __syncthreads();
        sm[t] += u;
        __syncthreads();
    }
    if (t < SNB) part[t] = sm[t] - v;   // exclusive
}

__global__ __launch_bounds__(256) void k_csrwrite(
    const int* __restrict__ cnt, const int* __restrict__ part,
    int* __restrict__ rowp, int* __restrict__ wof)
{
    int t = threadIdx.x;
    int i = blockIdx.x * SCH + t;
    int v = (i < NN) ? cnt[i] : 0;
    __shared__ int sm[256];
    sm[t] = v;
    __syncthreads();
    for (int off = 1; off < 256; off <<= 1) {
        int u = (t >= off) ? sm[t - off] : 0;
        __syncthreads();
        sm[t] += u;
        __syncthreads();
    }
    int excl = sm[t] - v + part[blockIdx.x];
    if (i < NN) { rowp[i] = excl; wof[i] = excl; }
    if (i == NN - 1) rowp[NN] = excl + v;   // = NE
}

// scatter (src, edge_attr) pairs into CSR order as int2
__global__ void k_scatter(const int* __restrict__ ei, const int* __restrict__ ea,
                          int* __restrict__ wof, int2* __restrict__ cse)
{
    int e = blockIdx.x * blockDim.x + threadIdx.x;
    if (e < NE) {
        int d = ei[NE + e];
        int pos = atomicAdd(&wof[d], 1);
        int2 v; v.x = ei[e]; v.y = ea[e];
        cse[pos] = v;
    }
}

// ---------------- x0b[n] = bf16(x0table[x[n]])  (+ fused gptr) ----------------
__global__ void k_x0(const int* __restrict__ x, const float* __restrict__ tab,
                     unsigned short* __restrict__ x0b,
                     const int* __restrict__ batch, int* __restrict__ gptr)
{
    int idx = blockIdx.x * blockDim.x + threadIdx.x;  // NN*32 float4 slots
    if (idx <= NGR) {
        if (idx == NGR) gptr[idx] = NN;
        else {
            int lo = 0, hi = NN;
            while (lo < hi) { int mid = (lo + hi) >> 1; if (batch[mid] < idx) lo = mid + 1; else hi = mid; }
            gptr[idx] = lo;
        }
    }
    if (idx >= NN * 32) return;
    int n = idx >> 5, c = idx & 31;
    float4 v = *(const float4*)&tab[x[n] * HD + c * 4];
    ushort4 u; u.x = f2bf(v.x); u.y = f2bf(v.y); u.z = f2bf(v.z); u.w = f2bf(v.w);
    *(ushort4*)&x0b[(size_t)n * HD + c * 4] = u;
}

// ---------------- bf16 MFMA GEMM (swapped operands) + LDS-staged stores -------
// R17: XCD-aware panel clustering. The 7 col-panels writing the SAME 64 rows
// get linear ids {n&7 + 8*(7*(n>>3)+p)} -> identical id%8 (same XCD under the
// round-robin dispatch heuristic) and adjacent dispatch order. Row writes
// complete while resident in ONE L2 -> full-line DRAM evictions; A re-reads
// become L2 hits. (R16 lesson: W was already cache-hit; FETCH was A re-reads,
// and write BW was page-thrash limited at 3.1 TB/s.)
__global__ __launch_bounds__(256) void k_gemm(
    const unsigned short* __restrict__ Ab, const unsigned short* __restrict__ Wpk,
    unsigned short* __restrict__ C)
{
    __shared__ unsigned short tile[64][136];
    int bid = blockIdx.x;
    int r8 = bid & 7, q = bid >> 3;
    int pan = q % GP;
    int nbk = (q / GP) * 8 + r8;
    if (nbk >= NBK) return;
    int nb = nbk * 64;
    int cb0 = pan * CBP;

    int lane = threadIdx.x & 63, wid = threadIdx.x >> 6;
    int rowl = wid * 16 + (lane & 15);
    int node = nb + rowl;
    size_t arow = (size_t)((node < NN) ? node : (NN - 1));
    int ko = (lane >> 4) << 3;
    const unsigned short* ap = Ab + arow * HD + ko;
    bf16x8 a0 = *(const bf16x8*)(ap);
    bf16x8 a1 = *(const bf16x8*)(ap + 32);
    bf16x8 a2 = *(const bf16x8*)(ap + 64);
    bf16x8 a3 = *(const bf16x8*)(ap + 96);

    const unsigned short* bp = Wpk + (size_t)cb0 * 512 + (size_t)lane * 8;
    int jreg = (lane >> 4) << 2;
#pragma unroll 4
    for (int i = 0; i < CBP; ++i) {
        bf16x8 w0 = *(const bf16x8*)(bp + i * 512);
        bf16x8 w1 = *(const bf16x8*)(bp + i * 512 + 28672);   // kb stride 56*512
        bf16x8 w2 = *(const bf16x8*)(bp + i * 512 + 57344);
        bf16x8 w3 = *(const bf16x8*)(bp + i * 512 + 86016);
        f32x4 acc = {0.f, 0.f, 0.f, 0.f};
        acc = __builtin_amdgcn_mfma_f32_16x16x32_bf16(w0, a0, acc, 0, 0, 0);
        acc = __builtin_amdgcn_mfma_f32_16x16x32_bf16(w1, a1, acc, 0, 0, 0);
        acc = __builtin_amdgcn_mfma_f32_16x16x32_bf16(w2, a2, acc, 0, 0, 0);
        acc = __builtin_amdgcn_mfma_f32_16x16x32_bf16(w3, a3, acc, 0, 0, 0);
        uint2 o;
        o.x = (unsigned)f2bf(acc[0]) | ((unsigned)f2bf(acc[1]) << 16);
        o.y = (unsigned)f2bf(acc[2]) | ((unsigned)f2bf(acc[3]) << 16);
        *(uint2*)&tile[rowl][i * 16 + jreg] = o;
    }
    __syncthreads();
    int r0 = threadIdx.x >> 4;            // 0..15
    int cseg = (threadIdx.x & 15) * 8;    // bf16 col offset, 16B per lane
#pragma unroll
    for (int pass = 0; pass < 4; ++pass) {
        int row = pass * 16 + r0;
        int gnode = nb + row;
        if (gnode < NN) {
            uint4 v = *(const uint4*)&tile[row][cseg];
            *(uint4*)&C[(size_t)gnode * NCAT + cb0 * 16 + cseg] = v;
        }
    }
}

// ---------------- per-node attention: ONE WAVE PER WORKGROUP ------------------
// (R15 win: independent wave retirement removes Poisson-degree stragglers.)
// Body: 2-edge ILP, packed f32x2 math, 32 VGPR.
__global__ __launch_bounds__(64) void k_edge(
    const unsigned short* __restrict__ QKVR,  // [NN][896] bf16, Q|KVint|R
    const unsigned short* __restrict__ etab,  // layer slice [30][256] bf16
    const float* __restrict__ attL, const float* __restrict__ biasL,
    const unsigned short* __restrict__ x0b,
    const int* __restrict__ rowptr, const int2* __restrict__ cse,
    unsigned short* __restrict__ hb)          // [NN][128] bf16
{
    int n = blockIdx.x;
    int lane = threadIdx.x & 63;
    int head = lane >> 5, sub = lane & 31;
    int col = head * HD + sub * 4;             // dim index (Q/etab/att layout)
    int kvo = 256 + head * 256 + sub * 8;      // KV-interleaved offset

    uint2 quu = *(const uint2*)&QKVR[(size_t)n * NCAT + col];
    f32x2 q0 = up2(quu.x), q1 = up2(quu.y);
    float4 a4 = *(const float4*)&attL[col];
    f32x2 av0 = {a4.x, a4.y}, av1 = {a4.z, a4.w};

    float l0 = 0.f, l1 = 0.f;
    f32x2 accA0 = {0.f, 0.f}, accA1 = {0.f, 0.f};
    f32x2 accB0 = {0.f, 0.f}, accB1 = {0.f, 0.f};

    int beg = rowptr[n], end = rowptr[n + 1];
    int idx = beg;
    for (; idx + 1 < end; idx += 2) {
        int2 seA = cse[idx];
        int2 seB = cse[idx + 1];
        uint4 kvA = *(const uint4*)&QKVR[(size_t)seA.x * NCAT + kvo];
        uint4 kvB = *(const uint4*)&QKVR[(size_t)seB.x * NCAT + kvo];
        uint2 euA = *(const uint2*)&etab[seA.y * CDIM + col];
        uint2 euB = *(const uint2*)&etab[seB.y * CDIM + col];

        f32x2 eA0 = up2(euA.x), eA1 = up2(euA.y);
        f32x2 eB0 = up2(euB.x), eB1 = up2(euB.y);

        f32x2 zA0 = lk2(q0 + up2(kvA.x) + eA0);
        f32x2 zA1 = lk2(q1 + up2(kvA.y) + eA1);
        f32x2 zB0 = lk2(q0 + up2(kvB.x) + eB0);
        f32x2 zB1 = lk2(q1 + up2(kvB.y) + eB1);

        f32x2 ppA = zA0 * av0 + zA1 * av1;
        f32x2 ppB = zB0 * av0 + zB1 * av1;
        float pA = ppA.x + ppA.y;
        float pB = ppB.x + ppB.y;
        pA += __shfl_xor(pA, 16); pB += __shfl_xor(pB, 16);
        pA += __shfl_xor(pA, 8);  pB += __shfl_xor(pB, 8);
        pA += __shfl_xor(pA, 4);  pB += __shfl_xor(pB, 4);
        pA += __shfl_xor(pA, 2);  pB += __shfl_xor(pB, 2);
        pA += __shfl_xor(pA, 1);  pB += __shfl_xor(pB, 1);
        float peA = __expf(fminf(fmaxf(pA, -30.f), 30.f));
        float peB = __expf(fminf(fmaxf(pB, -30.f), 30.f));

        accA0 += peA * (up2(kvA.z) + eA0);
        accA1 += peA * (up2(kvA.w) + eA1);
        accB0 += peB * (up2(kvB.z) + eB0);
        accB1 += peB * (up2(kvB.w) + eB1);
        l0 += peA;
        l1 += peB;
    }
    if (idx < end) {
        int2 se = cse[idx];
        uint4 kv = *(const uint4*)&QKVR[(size_t)se.x * NCAT + kvo];
        uint2 eu = *(const uint2*)&etab[se.y * CDIM + col];
        f32x2 e0 = up2(eu.x), e1 = up2(eu.y);
        f32x2 z0 = lk2(q0 + up2(kv.x) + e0);
        f32x2 z1 = lk2(q1 + up2(kv.y) + e1);
        f32x2 pp = z0 * av0 + z1 * av1;
        float p = pp.x + pp.y;
        p += __shfl_xor(p, 16); p += __shfl_xor(p, 8);
        p += __shfl_xor(p, 4);  p += __shfl_xor(p, 2); p += __shfl_xor(p, 1);
        float pe = __expf(fminf(fmaxf(p, -30.f), 30.f));
        accA0 += pe * (up2(kv.z) + e0);
        accA1 += pe * (up2(kv.w) + e1);
        l0 += pe;
    }
    float l = l0 + l1;
    float invl = (l > 0.f) ? 1.0f / l : 0.f;
    f32x2 r0 = (accA0 + accB0) * invl;
    f32x2 r1 = (accA1 + accB1) * invl;
    // mean over heads: pair lane <-> lane^32
    r0.x = 0.5f * (r0.x + __shfl_xor(r0.x, 32));
    r0.y = 0.5f * (r0.y + __shfl_xor(r0.y, 32));
    r1.x = 0.5f * (r1.x + __shfl_xor(r1.x, 32));
    r1.y = 0.5f * (r1.y + __shfl_xor(r1.y, 32));
    if (head == 0) {
        uint2 ruu = *(const uint2*)&QKVR[(size_t)n * NCAT + 768 + sub * 4];
        f32x2 ru0 = up2(ruu.x), ru1 = up2(ruu.y);
        float4 b4 = *(const float4*)&biasL[sub * 4];
        f32x2 bb0 = {b4.x, b4.y}, bb1 = {b4.z, b4.w};
        uint2 xuu = *(const uint2*)&x0b[(size_t)n * HD + sub * 4];
        f32x2 xx0 = up2(xuu.x), xx1 = up2(xuu.y);
        f32x2 zero = {0.f, 0.f};
        f32x2 h0 = 0.9f * __builtin_elementwise_max(r0 + ru0 + bb0, zero) + 0.1f * xx0;
        f32x2 h1 = 0.9f * __builtin_elementwise_max(r1 + ru1 + bb1, zero) + 0.1f * xx1;
        ushort4 o;
        o.x = f2bf(h0.x); o.y = f2bf(h0.y); o.z = f2bf(h1.x); o.w = f2bf(h1.y);
        *(ushort4*)&hb[(size_t)n * HD + sub * 4] = o;
    }
}

// ---------------- pooling: grid (graph, slice), vectorized uint2 loads --------
__global__ __launch_bounds__(256) void k_poolall(
    const unsigned short* __restrict__ x0b,
    const unsigned short* __restrict__ h0, const unsigned short* __restrict__ h1,
    const unsigned short* __restrict__ h2, const unsigned short* __restrict__ h3,
    const int* __restrict__ gptr, float* __restrict__ gsum)
{
    int g = blockIdx.x, sl = blockIdx.y;
    const unsigned short* src = (sl == 0) ? x0b : (sl == 1) ? h0 : (sl == 2) ? h1
                              : (sl == 3) ? h2 : h3;
    int q = threadIdx.x & 31;     // dim quad: dims q*4 .. q*4+3
    int r = threadIdx.x >> 5;     // row group 0..7
    int beg = gptr[g], end = gptr[g + 1];
    float sx = 0.f, sy = 0.f, sz = 0.f, sw = 0.f;
    for (int n = beg + r; n < end; n += 8) {
        uint2 u = *(const uint2*)&src[(size_t)n * HD + q * 4];
        sx += __uint_as_float(u.x << 16);
        sy += __uint_as_float(u.x & 0xffff0000u);
        sz += __uint_as_float(u.y << 16);
        sw += __uint_as_float(u.y & 0xffff0000u);
    }
    __shared__ float4 sm[8][32];
    float4 s4 = {sx, sy, sz, sw};
    sm[r][q] = s4;
    __syncthreads();
    if (r == 0) {
        float4 t = sm[0][q];
#pragma unroll
        for (int j = 1; j < 8; ++j) {
            float4 u = sm[j][q];
            t.x += u.x; t.y += u.y; t.z += u.z; t.w += u.w;
        }
        *(float4*)&gsum[(size_t)g * 640 + sl * HD + q * 4] = t;
    }
}

// ---------------- final MLP: g[640] -> 128 -> 1 ----------------
__global__ __launch_bounds__(128) void k_out(
    const float* __restrict__ gsum, const int* __restrict__ gptr,
    const float* __restrict__ w1, const float* __restrict__ b1,
    const float* __restrict__ g1, const float* __restrict__ bt1,
    const float* __restrict__ w2, const float* __restrict__ b2,
    float* __restrict__ out)
{
    int g = blockIdx.x, d = threadIdx.x;
    __shared__ float row[640];
    __shared__ float red[2];
    int c = gptr[g + 1] - gptr[g];
    float invc = 1.0f / (float)max(c, 1);
    for (int j = d; j < 640; j += 128) row[j] = gsum[(size_t)g * 640 + j] * invc;
    __syncthreads();
    float acc = b1[d];
    for (int j = 0; j < 640; ++j) acc += row[j] * w1[j * HD + d];
    float val = fmaxf(acc * BN_INV * g1[d] + bt1[d], 0.f);
    float part = val * w2[d];
    part += __shfl_xor(part, 32); part += __shfl_xor(part, 16);
    part += __shfl_xor(part, 8);  part += __shfl_xor(part, 4);
    part += __shfl_xor(part, 2);  part += __shfl_xor(part, 1);
    if ((threadIdx.x & 63) == 0) red[threadIdx.x >> 6] = part;
    __syncthreads();
    if (threadIdx.x == 0) out[g] = red[0] + red[1] + b2[0];
}

// ---------------- launch ----------------
extern "C" void kernel_launch(void* const* d_in, const int* in_sizes, int n_in,
                              void* d_out, int out_size, void* d_ws, size_t ws_size,
                              hipStream_t stream)
{
    const int*   x        = (const int*)d_in[0];
    const int*   ei       = (const int*)d_in[1];
    const int*   ea       = (const int*)d_in[2];
    const int*   batch    = (const int*)d_in[3];
    const float* node_emb = (const float*)d_in[4];
    const float* emb_w1   = (const float*)d_in[5];
    const float* emb_b1   = (const float*)d_in[6];
    const float* emb_g1   = (const float*)d_in[7];
    const float* emb_bt1  = (const float*)d_in[8];
    const float* emb_w2   = (const float*)d_in[9];
    const float* emb_b2   = (const float*)d_in[10];
    const float* bn0_g    = (const float*)d_in[11];
    const float* bn0_b    = (const float*)d_in[12];
    const float* Wq       = (const float*)d_in[13];
    const float* Wk       = (const float*)d_in[14];
    const float* Wv       = (const float*)d_in[15];
    const float* We       = (const float*)d_in[16];
    const float* att      = (const float*)d_in[17];
    const float* Wroot    = (const float*)d_in[18];
    const float* bias     = (const float*)d_in[19];
    const float* out_w1   = (const float*)d_in[20];
    const float* out_b1   = (const float*)d_in[21];
    const float* out_g1   = (const float*)d_in[22];
    const float* out_bt1  = (const float*)d_in[23];
    const float* out_w2   = (const float*)d_in[24];
    const float* out_b2   = (const float*)d_in[25];

    char* wp = (char*)d_ws;
    auto alloc = [&](size_t bytes) -> void* {
        void* p = (void*)wp;
        wp += (bytes + 255) & ~(size_t)255;
        return p;
    };
    unsigned short* x0b   = (unsigned short*)alloc((size_t)NN * HD * 2);
    unsigned short* hb0   = (unsigned short*)alloc((size_t)NN * HD * 2);
    unsigned short* hb1   = (unsigned short*)alloc((size_t)NN * HD * 2);
    unsigned short* hb2   = (unsigned short*)alloc((size_t)NN * HD * 2);
    unsigned short* hb3   = (unsigned short*)alloc((size_t)NN * HD * 2);
    unsigned short* QKVR  = (unsigned short*)alloc((size_t)NN * NCAT * 2);
    float*          x0tab = (float*)alloc((size_t)NVOC * HD * 4);
    unsigned short* etab  = (unsigned short*)alloc((size_t)NLAY * NVOC * CDIM * 2);
    unsigned short* Wpk   = (unsigned short*)alloc((size_t)NLAY * 224 * 64 * 8 * 2);
    int*   cnt   = (int*)alloc((size_t)NN * 4);
    int*   rowp  = (int*)alloc((size_t)(NN + 1) * 4);
    int*   wof   = (int*)alloc((size_t)(NN + 1) * 4);
    int*   part  = (int*)alloc((size_t)SNB * 4);
    int2*  cse   = (int2*)alloc((size_t)NE * 8);
    int*   gptr  = (int*)alloc((size_t)(NGR + 1) * 4);
    float* gsum  = (float*)alloc((size_t)NGR * 640 * 4);

    hipMemsetAsync(cnt, 0, (size_t)NN * 4, stream);

    k_setup<<<SU_NBLK, 256, 0, stream>>>(
        node_emb, emb_w1, emb_b1, emb_g1, emb_bt1, emb_w2, emb_b2, bn0_g, bn0_b,
        We, Wq, Wk, Wv, Wroot, ei, x0tab, etab, Wpk, cnt);
    k_blocksum<<<SNB, 256, 0, stream>>>(cnt, part);
    k_scanpart<<<1, 256, 0, stream>>>(part);
    k_csrwrite<<<SNB, 256, 0, stream>>>(cnt, part, rowp, wof);
    k_scatter<<<(NE + 255) / 256, 256, 0, stream>>>(ei, ea, wof, cse);
    k_x0<<<(NN * 32 + 255) / 256, 256, 0, stream>>>(x, x0tab, x0b, batch, gptr);

    const unsigned short* hin = x0b;
    unsigned short* houts[NLAY] = {hb0, hb1, hb2, hb3};
    for (int l = 0; l < NLAY; ++l) {
        k_gemm<<<GGRID, 256, 0, stream>>>(
            hin, Wpk + (size_t)l * 224 * 512, QKVR);
        k_edge<<<NN, 64, 0, stream>>>(
            QKVR, etab + (size_t)l * NVOC * CDIM, att + (size_t)l * CDIM, bias + (size_t)l * HD,
            x0b, rowp, cse, houts[l]);
        hin = houts[l];
    }
    k_poolall<<<dim3(NGR, 5), 256, 0, stream>>>(x0b, hb0, hb1, hb2, hb3, gptr, gsum);
    k_out<<<NGR, 128, 0, stream>>>(gsum, gptr, out_w1, out_b1, out_g1, out_bt1,
                                   out_w2, out_b2, (float*)d_out);
}